// Round 1
// baseline (560.823 us; speedup 1.0000x reference)
//
#include <hip/hip_runtime.h>
#include <stdint.h>

// ---------- types ----------
typedef short short4_t __attribute__((ext_vector_type(4)));
typedef short short8_t __attribute__((ext_vector_type(8)));
typedef float f32x4    __attribute__((ext_vector_type(4)));

__device__ __forceinline__ unsigned short f2bf(float f) {
  unsigned int u = __float_as_uint(f);
  u += 0x7FFFu + ((u >> 16) & 1u);          // round-to-nearest-even
  return (unsigned short)(u >> 16);
}

// ---------- kernel 1: min/max of conv_weight (36864 floats) ----------
__global__ __launch_bounds__(256) void minmax_kernel(const float* __restrict__ w,
                                                     float* __restrict__ mm) {
  int tid = threadIdx.x;
  float mn = 1e30f, mx = -1e30f;
  const float4* w4 = (const float4*)w;      // 9216 float4
  for (int i = tid; i < 9216; i += 256) {
    float4 v = w4[i];
    mn = fminf(mn, fminf(fminf(v.x, v.y), fminf(v.z, v.w)));
    mx = fmaxf(mx, fmaxf(fmaxf(v.x, v.y), fmaxf(v.z, v.w)));
  }
  for (int off = 32; off; off >>= 1) {
    mn = fminf(mn, __shfl_down(mn, off));
    mx = fmaxf(mx, __shfl_down(mx, off));
  }
  __shared__ float smn[4], smx[4];
  if ((tid & 63) == 0) { smn[tid >> 6] = mn; smx[tid >> 6] = mx; }
  __syncthreads();
  if (tid == 0) {
    mn = fminf(fminf(smn[0], smn[1]), fminf(smn[2], smn[3]));
    mx = fmaxf(fmaxf(smx[0], smx[1]), fmaxf(smx[2], smx[3]));
    mm[0] = mn; mm[1] = mx;
  }
}

// ---------- kernel 2: hash weights + transpose both sets to bf16 [tap][co][ci] ----------
__global__ __launch_bounds__(256) void hashprep_kernel(const float* __restrict__ w,
                                                       const float* __restrict__ hv,
                                                       const float* __restrict__ mm,
                                                       unsigned short* __restrict__ w0,
                                                       unsigned short* __restrict__ w1) {
  int t = blockIdx.x * 256 + threadIdx.x;   // 0..36863, layout [co][ci][kh][kw]
  if (t >= 36864) return;
  float mn = mm[0], mx = mm[1];
  float width = (mx - mn) / 256.0f;
  float wv = w[t];
  int idx = (int)floorf((wv - mn) / width); // matches reference fp32 math
  idx = min(max(idx, 0), 255);
  float hw = hv[idx];
  int co  = t / 576;
  int rem = t - co * 576;
  int ci  = rem / 9;
  int tap = rem - ci * 9;
  int dst = (tap * 64 + co) * 64 + ci;      // [tap][co][ci]
  w0[dst] = f2bf(wv);
  w1[dst] = f2bf(hw);
}

// ---------- kernel 3: conv via 9 shifted 1x1 GEMMs (MFMA bf16) ----------
// block: 256 thr = 4 waves; tile: 64 co x 64 px (one output row segment), all ci.
// NSETS=2: one input, two weight sets (out, hash_out). NSETS=1: out_hash.
template<int NSETS>
__global__ __launch_bounds__(256) void conv_kernel(
    const float* __restrict__ X,
    const unsigned short* __restrict__ Wg0,
    const unsigned short* __restrict__ Wg1,
    const float* __restrict__ bias,
    float* __restrict__ out0,
    float* __restrict__ out1) {

  __shared__ __align__(16) unsigned short Xs[3][66][68];      // [row][col][ci], ci padded ->68
  __shared__ __align__(16) unsigned short Ws[NSETS][64][72];  // [co][ci], ci padded ->72

  int bx = blockIdx.x;
  int w0 = (bx & 1) << 6;        // 0 or 64
  int h  = (bx >> 1) & 127;
  int b  = bx >> 8;

  int tid  = threadIdx.x;
  int lane = tid & 63;
  int wv   = tid >> 6;

  // ---- stage X tile: rows h-1..h+1, cols w0-1..w0+64, all 64 ci (bf16, zero-padded) ----
  for (int q = wv; q < 48; q += 4) {       // 48 quads: (row r, ci0=4k)
    int r   = q >> 4;                      // 0..2
    int ci0 = (q & 15) << 2;               // 0,4,...,60
    int hin = h + r - 1;
    bool rowok = (unsigned)hin < 128u;
    for (int cb = 0; cb < 128; cb += 64) {
      int col = cb + lane;
      if (col < 66) {
        int win = w0 + col - 1;
        bool ok = rowok && ((unsigned)win < 128u);
        float v0 = 0.f, v1 = 0.f, v2 = 0.f, v3 = 0.f;
        if (ok) {
          const float* p = X + (((size_t)(b * 64 + ci0) * 128 + hin) * 128 + win);
          v0 = p[0]; v1 = p[16384]; v2 = p[32768]; v3 = p[49152];
        }
        *(ushort4*)&Xs[r][col][ci0] = make_ushort4(f2bf(v0), f2bf(v1), f2bf(v2), f2bf(v3));
      }
    }
  }

  f32x4 acc[NSETS][4];
  #pragma unroll
  for (int s = 0; s < NSETS; ++s)
    #pragma unroll
    for (int n = 0; n < 4; ++n) acc[s][n] = (f32x4){0.f, 0.f, 0.f, 0.f};

  int m = lane & 15, g = lane >> 4;

  for (int t = 0; t < 9; ++t) {
    __syncthreads();                        // prev tap's A-reads done (also covers X staging)
    {   // stage W tap t (contiguous 8KB per set)
      const ushort4* src0 = (const ushort4*)(Wg0 + t * 4096);
      for (int j = tid; j < 1024; j += 256) {
        ushort4 v = src0[j];
        *(ushort4*)&Ws[0][j >> 4][(j & 15) << 2] = v;
      }
      if (NSETS == 2) {
        const ushort4* src1 = (const ushort4*)(Wg1 + t * 4096);
        for (int j = tid; j < 1024; j += 256) {
          ushort4 v = src1[j];
          *(ushort4*)&Ws[1][j >> 4][(j & 15) << 2] = v;
        }
      }
    }
    __syncthreads();

    int kh = t / 3, kw = t - kh * 3;

    // B fragments: B[k=ci][n=px], n = 16*nf + m, k = 4g + (i&3) + 16*(i>>2) + 32*ks
    short8_t bf[4][2];
    #pragma unroll
    for (int nf = 0; nf < 4; ++nf) {
      int col = nf * 16 + m + kw;           // Xs col = px + kw
      #pragma unroll
      for (int ks = 0; ks < 2; ++ks) {
        int ci = g * 4 + ks * 32;
        short4_t lo = *(const short4_t*)&Xs[kh][col][ci];
        short4_t hi = *(const short4_t*)&Xs[kh][col][ci + 16];
        bf[nf][ks] = __builtin_shufflevector(lo, hi, 0, 1, 2, 3, 4, 5, 6, 7);
      }
    }
    #pragma unroll
    for (int s = 0; s < NSETS; ++s) {
      #pragma unroll
      for (int ks = 0; ks < 2; ++ks) {
        int ci = g * 4 + ks * 32;
        const unsigned short* wr = &Ws[s][wv * 16 + m][0];
        short4_t lo = *(const short4_t*)(wr + ci);
        short4_t hi = *(const short4_t*)(wr + ci + 16);
        short8_t af = __builtin_shufflevector(lo, hi, 0, 1, 2, 3, 4, 5, 6, 7);
        #pragma unroll
        for (int nf = 0; nf < 4; ++nf)
          acc[s][nf] = __builtin_amdgcn_mfma_f32_16x16x32_bf16(af, bf[nf][ks], acc[s][nf], 0, 0, 0);
      }
    }
  }

  // ---- epilogue: D row = co = 16*wv + 4g + rr, col = px = 16*nf + m ----
  size_t pbase = ((size_t)(b * 64) * 128 + h) * 128 + w0;
  #pragma unroll
  for (int s = 0; s < NSETS; ++s) {
    float* op = s ? out1 : out0;
    #pragma unroll
    for (int rr = 0; rr < 4; ++rr) {
      int co = wv * 16 + g * 4 + rr;
      float bv = bias[co];
      #pragma unroll
      for (int nf = 0; nf < 4; ++nf)
        op[pbase + (size_t)co * 16384 + nf * 16 + m] = acc[s][nf][rr] + bv;
    }
  }
}

// ---------- launch ----------
extern "C" void kernel_launch(void* const* d_in, const int* in_sizes, int n_in,
                              void* d_out, int out_size, void* d_ws, size_t ws_size,
                              hipStream_t stream) {
  const float* x    = (const float*)d_in[0];
  const float* xh   = (const float*)d_in[1];
  const float* cw   = (const float*)d_in[2];
  const float* hv   = (const float*)d_in[3];
  const float* bias = (const float*)d_in[4];

  float* out      = (float*)d_out;            // 16*64*128*128
  float* hash_out = out + 16777216;
  float* out_hash = out + 33554432;

  float* mm          = (float*)d_ws;
  unsigned short* w0 = (unsigned short*)((char*)d_ws + 16);   // [9][64][64] bf16
  unsigned short* w1 = w0 + 36864;

  minmax_kernel<<<1, 256, 0, stream>>>(cw, mm);
  hashprep_kernel<<<144, 256, 0, stream>>>(cw, hv, mm, w0, w1);
  conv_kernel<2><<<4096, 256, 0, stream>>>(x,  w0, w1, bias, out, hash_out);
  conv_kernel<1><<<4096, 256, 0, stream>>>(xh, w1, w1, bias, out_hash, out_hash);
}

// Round 3
// 389.145 us; speedup vs baseline: 1.4412x; 1.4412x over previous
//
#include <hip/hip_runtime.h>
#include <stdint.h>

typedef short short8_t __attribute__((ext_vector_type(8)));
typedef float f32x4    __attribute__((ext_vector_type(4)));

__device__ __forceinline__ unsigned short f2bf(float f) {
  unsigned int u = __float_as_uint(f);
  u += 0x7FFFu + ((u >> 16) & 1u);          // round-to-nearest-even
  return (unsigned short)(u >> 16);
}

// async global->LDS, 16B per lane; LDS dest = wave-uniform base + lane*16
__device__ __forceinline__ void glld16(const void* src, char* lds) {
  __builtin_amdgcn_global_load_lds(
      (const __attribute__((address_space(1))) void*)src,
      (__attribute__((address_space(3))) void*)lds, 16, 0, 0);
}

// swizzled b128 LDS read: XOR bits 4-6 keyed on bits 7-9 (matches pre-swizzled source)
__device__ __forceinline__ short8_t lds_rd(const char* smem, int a) {
  int aa = a ^ (((a >> 7) & 7) << 4);
  return *(const short8_t*)(smem + aa);
}

// ---------- kernel 1: min/max of conv_weight ----------
__global__ __launch_bounds__(256) void minmax_kernel(const float* __restrict__ w,
                                                     float* __restrict__ mm) {
  int tid = threadIdx.x;
  float mn = 1e30f, mx = -1e30f;
  const float4* w4 = (const float4*)w;      // 9216 float4
  for (int i = tid; i < 9216; i += 256) {
    float4 v = w4[i];
    mn = fminf(mn, fminf(fminf(v.x, v.y), fminf(v.z, v.w)));
    mx = fmaxf(mx, fmaxf(fmaxf(v.x, v.y), fmaxf(v.z, v.w)));
  }
  for (int off = 32; off; off >>= 1) {
    mn = fminf(mn, __shfl_down(mn, off));
    mx = fmaxf(mx, __shfl_down(mx, off));
  }
  __shared__ float smn[4], smx[4];
  if ((tid & 63) == 0) { smn[tid >> 6] = mn; smx[tid >> 6] = mx; }
  __syncthreads();
  if (tid == 0) {
    mn = fminf(fminf(smn[0], smn[1]), fminf(smn[2], smn[3]));
    mx = fmaxf(fmaxf(smx[0], smx[1]), fmaxf(smx[2], smx[3]));
    mm[0] = mn; mm[1] = mx;
  }
}

// ---------- kernel 2: hash weights + both sets bf16 [tap][co][ci] ----------
__global__ __launch_bounds__(256) void hashprep_kernel(const float* __restrict__ w,
                                                       const float* __restrict__ hv,
                                                       const float* __restrict__ mm,
                                                       unsigned short* __restrict__ w0,
                                                       unsigned short* __restrict__ w1) {
  int t = blockIdx.x * 256 + threadIdx.x;   // 0..36863, layout [co][ci][kh][kw]
  if (t >= 36864) return;
  float mn = mm[0], mx = mm[1];
  float width = (mx - mn) / 256.0f;
  float wv = w[t];
  int idx = (int)floorf((wv - mn) / width);
  idx = min(max(idx, 0), 255);
  float hw = hv[idx];
  int co  = t / 576;
  int rem = t - co * 576;
  int ci  = rem / 9;
  int tap = rem - ci * 9;
  int dst = (tap * 64 + co) * 64 + ci;      // [tap][co][ci]
  w0[dst] = f2bf(wv);
  w1[dst] = f2bf(hw);
}

// ---------- kernel 3: x (f32 NCHW) -> Xbf (bf16 [b][h][w' 0..129][ci]), w-halo zeroed ----------
__global__ __launch_bounds__(256) void xprep_kernel(const float* __restrict__ x,
                                                    unsigned short* __restrict__ xbf) {
  int t = blockIdx.x * 256 + threadIdx.x;   // 16*128*130*8 = 2,129,920 exact
  int c8 = t & 7;
  int w  = (t >> 3) % 130;
  int bh = (t >> 3) / 130;                  // b*128 + h
  short8_t v;
  #pragma unroll
  for (int j = 0; j < 8; ++j) v[j] = 0;
  if (w != 0 && w != 129) {
    const float* p = x + (((size_t)(bh >> 7) * 64 + c8 * 8) * 128 + (bh & 127)) * 128 + (w - 1);
    #pragma unroll
    for (int j = 0; j < 8; ++j) v[j] = (short)f2bf(p[(size_t)j * 16384]);
  }
  *(short8_t*)(xbf + (size_t)t * 8) = v;
}

// ---------- kernel 4: conv via 9 shifted 1x1 GEMMs ----------
// 8 waves (512 thr); block = 64co x 4 h-rows x 128 w. Wave = 64co x 64px x NSETS.
// X: LDS [6][130][64] bf16 (99840B) staged once via global_load_lds (pre-swizzled src).
// W: per-tap [2buf][NSETS][64][64] double-buffered, staged 1 tap ahead -> 1 barrier/tap.
#define XROW 16640
#define WSB  99840

template<int NSETS>
__global__ __launch_bounds__(512, 2) void conv_kernel(
    const unsigned short* __restrict__ xbf,
    const char* __restrict__ zeropage,      // 16640 zeroed bytes
    const unsigned short* __restrict__ wg0,
    const unsigned short* __restrict__ wg1,
    const float* __restrict__ bias,
    float* __restrict__ out0,
    float* __restrict__ out1) {

  extern __shared__ char smem[];
  const int BUFSTRIDE = NSETS * 8192;

  int tid = threadIdx.x, lane = tid & 63, wv = tid >> 6;
  int m = lane & 15, g = (lane >> 4) & 3;
  int rr = wv >> 1, wseg = (wv & 1) << 6;

  int bx = blockIdx.x;
  int b = bx >> 5, h0 = (bx & 31) << 2;

  // ---- stage X: 6 rows (h0-1 .. h0+4) x 16640B, linear LDS dest, swizzled source ----
  const char* xb = (const char*)xbf + (size_t)b * (130 * 128 * 128);
  for (int batch = wv; batch < 98; batch += 8) {
    int q = batch * 64 + lane;              // 16B chunk id, 6240 total
    if (q < 6240) {
      int r    = q / 1040;                  // row 0..5
      int o_in = (q - r * 1040) << 4;       // byte offset within row
      int swz  = o_in ^ (((q >> 3) & 7) << 4);
      int hin  = h0 + r - 1;
      const char* src = ((unsigned)hin < 128u) ? (xb + (size_t)hin * XROW + swz)
                                               : (zeropage + swz);
      glld16(src, smem + batch * 1024);
    }
  }

  // ---- W staging helper (swizzled source), tap t into buffer buf ----
  auto stage_w = [&](int t, int buf) {
    for (int batch = wv; batch < NSETS * 8; batch += 8) {
      int q    = batch * 64 + lane;         // < NSETS*512
      int s    = q >> 9;
      int o_in = (q & 511) << 4;
      int key  = (4 + (q >> 3)) & 7;        // (WSB>>7)&7 == 4
      int swz  = o_in ^ (key << 4);
      const char* src = (const char*)(s ? wg1 : wg0) + t * 8192 + swz;
      glld16(src, smem + WSB + buf * BUFSTRIDE + batch * 1024);
    }
  };

  f32x4 acc[NSETS][4][4];
  #pragma unroll
  for (int s = 0; s < NSETS; ++s)
    #pragma unroll
    for (int i = 0; i < 4; ++i)
      #pragma unroll
      for (int j = 0; j < 4; ++j) acc[s][i][j] = (f32x4){0.f, 0.f, 0.f, 0.f};

  int arow[4], bcol[4];
  #pragma unroll
  for (int i = 0; i < 4; ++i) {
    arow[i] = ((i * 16 + m) << 7) + (g << 4);
    bcol[i] = ((wseg + i * 16 + m) << 7) + (g << 4);
  }

  stage_w(0, 0);
  __syncthreads();                          // drains X + W0 (vmcnt0 at barrier)

  #pragma unroll
  for (int t = 0; t < 9; ++t) {
    if (t < 8) stage_w(t + 1, (t + 1) & 1); // prefetch next tap (other buffer)
    int kh = t / 3, kw = t - kh * 3;
    int xtap  = (rr + kh) * XROW + (kw << 7);
    int wbase = WSB + (t & 1) * BUFSTRIDE;
    #pragma unroll
    for (int ks = 0; ks < 2; ++ks) {
      int ko = ks << 6;
      short8_t bf[4];
      #pragma unroll
      for (int nf = 0; nf < 4; ++nf) bf[nf] = lds_rd(smem, xtap + bcol[nf] + ko);
      #pragma unroll
      for (int mt = 0; mt < 4; ++mt) {
        short8_t a0 = lds_rd(smem, wbase + arow[mt] + ko);
        #pragma unroll
        for (int nf = 0; nf < 4; ++nf)
          acc[0][mt][nf] = __builtin_amdgcn_mfma_f32_16x16x32_bf16(a0, bf[nf], acc[0][mt][nf], 0, 0, 0);
        if (NSETS == 2) {
          short8_t a1 = lds_rd(smem, wbase + 8192 + arow[mt] + ko);
          #pragma unroll
          for (int nf = 0; nf < 4; ++nf)
            acc[1][mt][nf] = __builtin_amdgcn_mfma_f32_16x16x32_bf16(a1, bf[nf], acc[1][mt][nf], 0, 0, 0);
        }
      }
    }
    __syncthreads();                        // next-tap W landed; buf t&1 free for reuse
  }

  // ---- epilogue: D col = px = wseg+nf*16+m, row = co = mt*16+4g+r4 ----
  size_t ob = (size_t)b * 64 * 16384 + (size_t)(h0 + rr) * 128 + wseg;
  #pragma unroll
  for (int s = 0; s < NSETS; ++s) {
    float* op = s ? out1 : out0;
    #pragma unroll
    for (int mt = 0; mt < 4; ++mt)
      #pragma unroll
      for (int r4 = 0; r4 < 4; ++r4) {
        int co = mt * 16 + g * 4 + r4;
        float bv = bias[co];
        #pragma unroll
        for (int nf = 0; nf < 4; ++nf)
          op[ob + (size_t)co * 16384 + nf * 16 + m] = acc[s][mt][nf][r4] + bv;
      }
  }
}

// ---------- launch ----------
extern "C" void kernel_launch(void* const* d_in, const int* in_sizes, int n_in,
                              void* d_out, int out_size, void* d_ws, size_t ws_size,
                              hipStream_t stream) {
  const float* x    = (const float*)d_in[0];
  const float* xh   = (const float*)d_in[1];
  const float* cw   = (const float*)d_in[2];
  const float* hv   = (const float*)d_in[3];
  const float* bias = (const float*)d_in[4];

  float* out      = (float*)d_out;
  float* hash_out = out + 16777216;
  float* out_hash = out + 33554432;

  char* ws = (char*)d_ws;
  float* mm            = (float*)ws;
  char* zeropage       = ws + 128;                       // 16640 B
  unsigned short* w0   = (unsigned short*)(ws + 32768);  // [9][64][64] bf16
  unsigned short* w1   = (unsigned short*)(ws + 32768 + 73728);
  unsigned short* xbf  = (unsigned short*)(ws + 180224); // 34,078,720 B

  hipMemsetAsync(zeropage, 0, 16640, stream);
  minmax_kernel<<<1, 256, 0, stream>>>(cw, mm);
  hashprep_kernel<<<144, 256, 0, stream>>>(cw, hv, mm, w0, w1);

  (void)hipFuncSetAttribute((const void*)conv_kernel<2>,
                            hipFuncAttributeMaxDynamicSharedMemorySize, 99840 + 32768);
  (void)hipFuncSetAttribute((const void*)conv_kernel<1>,
                            hipFuncAttributeMaxDynamicSharedMemorySize, 99840 + 16384);

  xprep_kernel<<<8320, 256, 0, stream>>>(x, xbf);
  conv_kernel<2><<<512, 512, 99840 + 32768, stream>>>(xbf, zeropage, w0, w1, bias, out, hash_out);
  xprep_kernel<<<8320, 256, 0, stream>>>(xh, xbf);
  conv_kernel<1><<<512, 512, 99840 + 16384, stream>>>(xbf, zeropage, w1, w1, bias, out_hash, out_hash);
}